// Round 5
// baseline (1875.987 us; speedup 1.0000x reference)
//
#include <hip/hip_runtime.h>

#define NN 100000
#define NE 3200000
#define DIN 128
#define HD 64
#define DEMB 32
#define NG 256
#define NBUCK ((NN + 255) / 256)   // 391 coarse buckets of 256 dst-nodes

// ---------------- coarse histogram over dst>>8 (LDS-aggregated) --------------
__global__ void k_chist(const int* __restrict__ dst, int* __restrict__ ccnt, int E) {
    __shared__ int h[NBUCK];
    for (int i = threadIdx.x; i < NBUCK; i += blockDim.x) h[i] = 0;
    __syncthreads();
    int i = blockIdx.x * blockDim.x + threadIdx.x;
    int stride = gridDim.x * blockDim.x;
    for (; i < E; i += stride) atomicAdd(&h[dst[i] >> 8], 1);
    __syncthreads();
    for (int j = threadIdx.x; j < NBUCK; j += blockDim.x)
        if (h[j]) atomicAdd(&ccnt[j], h[j]);
}

// ---------------- coarse scan (one block, 512 threads) -----------------------
__global__ __launch_bounds__(512) void k_cscan(const int* __restrict__ ccnt,
                                               int* __restrict__ crow,
                                               int* __restrict__ ccur) {
    __shared__ int s[512];
    int t = threadIdx.x;
    int v = (t < NBUCK) ? ccnt[t] : 0;
    s[t] = v;
    __syncthreads();
    for (int off = 1; off < 512; off <<= 1) {
        int add = (t >= off) ? s[t - off] : 0;
        __syncthreads();
        s[t] += add;
        __syncthreads();
    }
    if (t < NBUCK) { int e = s[t] - v; crow[t] = e; ccur[t] = e; }
    if (t == NBUCK - 1) crow[NBUCK] = s[t];
}

// ---------------- partition edges into coarse buckets (packed payload) -------
// part[pos] = src | (dst&255)<<17   (src < 2^17, dlow < 2^8)
__global__ void k_partition(const int* __restrict__ src, const int* __restrict__ dst,
                            int* __restrict__ ccur, int* __restrict__ part, int E) {
    int i = blockIdx.x * blockDim.x + threadIdx.x;
    int stride = gridDim.x * blockDim.x;
    for (; i < E; i += stride) {
        int d = dst[i];
        int s = src[i];
        int pos = atomicAdd(&ccur[d >> 8], 1);
        part[pos] = s | ((d & 255) << 17);
    }
}

// ---------------- phase B: per-bucket fine sort + degree + rowptr + dinv -----
__global__ __launch_bounds__(256) void k_phaseB(const int* __restrict__ part,
                                                const int* __restrict__ crow,
                                                int* __restrict__ rowptr,
                                                int* __restrict__ ssrc,
                                                float* __restrict__ dinv, int E) {
    __shared__ int cnt[256];
    __shared__ int sc[256];
    int b = blockIdx.x;
    int t = threadIdx.x;
    int beg = crow[b], end = crow[b + 1];
    int node0 = b << 8;
    int nnode = NN - node0 < 256 ? NN - node0 : 256;
    cnt[t] = 0;
    __syncthreads();
    for (int j = beg + t; j < end; j += 256) atomicAdd(&cnt[part[j] >> 17], 1);
    __syncthreads();
    int v = cnt[t];
    sc[t] = v;
    __syncthreads();
    for (int off = 1; off < 256; off <<= 1) {
        int add = (t >= off) ? sc[t - off] : 0;
        __syncthreads();
        sc[t] += add;
        __syncthreads();
    }
    int excl = sc[t] - v;
    if (t < nnode) {
        rowptr[node0 + t] = beg + excl;
        dinv[node0 + t] = rsqrtf((float)v + 1.0f);
    }
    if (b == NBUCK - 1 && t == 0) rowptr[NN] = E;
    __syncthreads();
    cnt[t] = beg + excl;    // reuse as cursor
    __syncthreads();
    for (int j = beg + t; j < end; j += 256) {
        int e = part[j];
        int pos = atomicAdd(&cnt[e >> 17], 1);
        ssrc[pos] = e & 0x1FFFF;
    }
}

// ---------------- GEMM: U[n][64] = (X[n][K] @ W[K][64]) * dinv[row] ----------
template <int K>
__global__ void k_gemm(const float* __restrict__ X, const float* __restrict__ W,
                       const float* __restrict__ dinv, float* __restrict__ U, int n) {
    __shared__ __align__(16) float wl[K * 64];
    __shared__ __align__(16) float xs[16][K];
    int tid = threadIdx.x;
    for (int i = tid; i < K * 64; i += 256) wl[i] = W[i];
    int cg = tid & 15;
    int rs = tid >> 4;
    int ngrp = (n + 15) >> 4;
    for (int grp = blockIdx.x; grp < ngrp; grp += gridDim.x) {
        int row0 = grp * 16;
        __syncthreads();
        for (int i = tid; i < 16 * K; i += 256) {
            int r = i / K, c = i % K;
            int row = row0 + r;
            xs[r][c] = (row < n) ? X[(size_t)row * K + c] : 0.0f;
        }
        __syncthreads();
        float4 acc = {0.f, 0.f, 0.f, 0.f};
#pragma unroll 8
        for (int k = 0; k < K; k++) {
            float xv = xs[rs][k];
            float4 w4 = *reinterpret_cast<const float4*>(&wl[k * 64 + cg * 4]);
            acc.x += xv * w4.x;
            acc.y += xv * w4.y;
            acc.z += xv * w4.z;
            acc.w += xv * w4.w;
        }
        int row = row0 + rs;
        if (row < n) {
            float dv = dinv[row];
            acc.x *= dv; acc.y *= dv; acc.z *= dv; acc.w *= dv;
            *reinterpret_cast<float4*>(&U[(size_t)row * 64 + cg * 4]) = acc;
        }
    }
}

// ---------------- gather-reduce per dst node ----------------------------------
// h[d] = relu(dinv[d] * (sum_{s in N(d)} U[s] + U[d]) + b)
template <bool FUSE_POOL>
__global__ void k_gather(const int* __restrict__ rowptr, const int* __restrict__ ssrc,
                         const float* __restrict__ dinv, const float* __restrict__ U,
                         const float* __restrict__ bias, const int* __restrict__ batch,
                         float* __restrict__ outbuf, int n) {
    int gtid = blockIdx.x * blockDim.x + threadIdx.x;
    int lane = gtid & 63;
    int g = lane >> 4;       // edge sub-index within a 4-edge chunk
    int c = lane & 15;       // float4 chunk within the 64-ch row
    int w = gtid >> 6;
    int nw = (gridDim.x * blockDim.x) >> 6;
    float4 bv = *reinterpret_cast<const float4*>(&bias[c * 4]);
    for (int d = w; d < n; d += nw) {
        int beg = rowptr[d], end = rowptr[d + 1];
        float4 acc0 = {0.f, 0.f, 0.f, 0.f};
        float4 acc1 = {0.f, 0.f, 0.f, 0.f};
        int j = beg;
        for (; j + 8 <= end; j += 8) {
            int s0 = ssrc[j + g];
            int s1 = ssrc[j + 4 + g];
            float4 v0 = *reinterpret_cast<const float4*>(&U[(size_t)s0 * 64 + c * 4]);
            float4 v1 = *reinterpret_cast<const float4*>(&U[(size_t)s1 * 64 + c * 4]);
            acc0.x += v0.x; acc0.y += v0.y; acc0.z += v0.z; acc0.w += v0.w;
            acc1.x += v1.x; acc1.y += v1.y; acc1.z += v1.z; acc1.w += v1.w;
        }
        if (j + 4 <= end) {
            int s0 = ssrc[j + g];
            float4 v0 = *reinterpret_cast<const float4*>(&U[(size_t)s0 * 64 + c * 4]);
            acc0.x += v0.x; acc0.y += v0.y; acc0.z += v0.z; acc0.w += v0.w;
            j += 4;
        }
        if (j + g < end) {
            int s1 = ssrc[j + g];
            float4 v1 = *reinterpret_cast<const float4*>(&U[(size_t)s1 * 64 + c * 4]);
            acc1.x += v1.x; acc1.y += v1.y; acc1.z += v1.z; acc1.w += v1.w;
        }
        acc0.x += acc1.x; acc0.y += acc1.y; acc0.z += acc1.z; acc0.w += acc1.w;
        acc0.x += __shfl_xor(acc0.x, 16); acc0.y += __shfl_xor(acc0.y, 16);
        acc0.z += __shfl_xor(acc0.z, 16); acc0.w += __shfl_xor(acc0.w, 16);
        acc0.x += __shfl_xor(acc0.x, 32); acc0.y += __shfl_xor(acc0.y, 32);
        acc0.z += __shfl_xor(acc0.z, 32); acc0.w += __shfl_xor(acc0.w, 32);
        float4 ud = *reinterpret_cast<const float4*>(&U[(size_t)d * 64 + c * 4]);
        float dd = dinv[d];
        float4 h;
        h.x = (acc0.x + ud.x) * dd + bv.x;
        h.y = (acc0.y + ud.y) * dd + bv.y;
        h.z = (acc0.z + ud.z) * dd + bv.z;
        h.w = (acc0.w + ud.w) * dd + bv.w;
        h.x = h.x > 0.f ? h.x : 0.f;
        h.y = h.y > 0.f ? h.y : 0.f;
        h.z = h.z > 0.f ? h.z : 0.f;
        h.w = h.w > 0.f ? h.w : 0.f;
        if (FUSE_POOL) {
            if (g == 0) {
                float* sp = &outbuf[(size_t)batch[d] * 64 + c * 4];
                atomicAdd(sp + 0, h.x);
                atomicAdd(sp + 1, h.y);
                atomicAdd(sp + 2, h.z);
                atomicAdd(sp + 3, h.w);
            }
        } else {
            if (g == 0) {
                *reinterpret_cast<float4*>(&outbuf[(size_t)d * 64 + c * 4]) = h;
            }
        }
    }
}

// ---------------- per-graph node counts ---------------------------------------
__global__ void k_cnt(const int* __restrict__ batch, float* __restrict__ cnt, int n) {
    int i = blockIdx.x * blockDim.x + threadIdx.x;
    if (i < n) atomicAdd(&cnt[batch[i]], 1.0f);
}

// ---------------- head: out[g] = (sums[g]/cnt[g]) @ Wl + bl ------------------
__global__ void k_final(const float* __restrict__ sums, const float* __restrict__ cnt,
                        const float* __restrict__ Wl, const float* __restrict__ bl,
                        float* __restrict__ out) {
    __shared__ float pooled[64];
    int g = blockIdx.x;
    int t = threadIdx.x;
    float c = cnt[g];
    c = c < 1.0f ? 1.0f : c;
    pooled[t] = sums[g * 64 + t] / c;
    __syncthreads();
    if (t < 32) {
        float acc = bl[t];
#pragma unroll 8
        for (int k = 0; k < 64; k++) acc += pooled[k] * Wl[k * 32 + t];
        out[g * 32 + t] = acc;
    }
}

extern "C" void kernel_launch(void* const* d_in, const int* in_sizes, int n_in,
                              void* d_out, int out_size, void* d_ws, size_t ws_size,
                              hipStream_t stream) {
    const float* x = (const float*)d_in[0];
    const int* ei = (const int*)d_in[1];      // [2, E] int32
    const int* batch = (const int*)d_in[2];   // [N] int32
    const float* W1 = (const float*)d_in[4];
    const float* b1 = (const float*)d_in[5];
    const float* W2 = (const float*)d_in[6];
    const float* b2 = (const float*)d_in[7];
    const float* Wl = (const float*)d_in[8];
    const float* bl = (const float*)d_in[9];
    float* out = (float*)d_out;

    const int* esrc = ei;
    const int* edst = ei + NE;

    char* ws = (char*)d_ws;
    size_t off = 0;
    auto alloc = [&](size_t bytes) {
        void* p = ws + off;
        off += (bytes + 255) & ~size_t(255);
        return p;
    };
    float* dinv   = (float*)alloc((size_t)NN * 4);
    int*   rowptr = (int*)alloc((size_t)(NN + 1) * 4);
    int*   ccnt   = (int*)alloc((size_t)(NBUCK + 1) * 4);
    int*   crow   = (int*)alloc((size_t)(NBUCK + 1) * 4);
    int*   ccur   = (int*)alloc((size_t)(NBUCK + 1) * 4);
    int*   ssrc   = (int*)alloc((size_t)NE * 4);        // 12.8 MB
    float* tbuf   = (float*)alloc((size_t)NN * HD * 4); // 25.6 MB
    float* agg    = (float*)alloc((size_t)NN * HD * 4); // 25.6 MB
    float* sums   = (float*)alloc((size_t)NG * HD * 4);
    float* cnt    = (float*)alloc((size_t)NG * 4);
    // part overlays tbuf: dead before gemm1 writes tbuf
    int* part = (int*)tbuf;

    // 1. two-phase counting sort -> ssrc (+ rowptr, dinv)
    hipMemsetAsync(ccnt, 0, (size_t)(NBUCK + 1) * 4, stream);
    k_chist<<<1024, 256, 0, stream>>>(edst, ccnt, NE);
    k_cscan<<<1, 512, 0, stream>>>(ccnt, crow, ccur);
    k_partition<<<2048, 256, 0, stream>>>(esrc, edst, ccur, part, NE);
    k_phaseB<<<NBUCK, 256, 0, stream>>>(part, crow, rowptr, ssrc, dinv, NE);

    // 2. layer 1: U1 = (x@W1)*dinv ; h1 = relu(dinv*(gather+self) + b1) -> agg
    k_gemm<DIN><<<512, 256, 0, stream>>>(x, W1, dinv, tbuf, NN);
    k_gather<false><<<2048, 256, 0, stream>>>(rowptr, ssrc, dinv, tbuf, b1, batch, agg, NN);

    // 3. layer 2: U2 = (h1@W2)*dinv ; h2 rows scattered straight into pool sums
    k_gemm<HD><<<512, 256, 0, stream>>>(agg, W2, dinv, tbuf, NN);
    hipMemsetAsync(sums, 0, (size_t)(NG * HD + NG) * 4, stream);  // sums + cnt
    k_cnt<<<(NN + 255) / 256, 256, 0, stream>>>(batch, cnt, NN);
    k_gather<true><<<2048, 256, 0, stream>>>(rowptr, ssrc, dinv, tbuf, b2, batch, sums, NN);

    // 4. head
    k_final<<<NG, 64, 0, stream>>>(sums, cnt, Wl, bl, out);
}

// Round 6
// 795.000 us; speedup vs baseline: 2.3597x; 2.3597x over previous
//
#include <hip/hip_runtime.h>

#define NN 100000
#define NE 3200000
#define DIN 128
#define HD 64
#define DEMB 32
#define NG 256
#define NBUCK ((NN + 255) / 256)        // 391 coarse buckets of 256 dst-nodes
#define NPB 512                         // partition blocks
#define CHUNK ((NE + NPB - 1) / NPB)    // 6250 edges per partition block
#define NM (NBUCK * NPB)                // 200192 histogram-matrix entries
#define NMB ((NM + 1023) / 1024)        // 196 scan blocks

// ---------------- pass A: per-block coarse histogram (no global atomics) -----
__global__ __launch_bounds__(256) void k_blkhist(const int* __restrict__ dst,
                                                 int* __restrict__ HM, int E) {
    __shared__ int h[NBUCK];
    int blk = blockIdx.x, t = threadIdx.x;
    for (int i = t; i < NBUCK; i += 256) h[i] = 0;
    __syncthreads();
    int beg = blk * CHUNK, end = min(E, beg + CHUNK);
    for (int j = beg + t; j < end; j += 256) atomicAdd(&h[dst[j] >> 8], 1);
    __syncthreads();
    for (int i = t; i < NBUCK; i += 256) HM[i * NPB + blk] = h[i];  // bucket-major
}

// ---------------- scan pass 1: in-place per-1024-block exclusive scan --------
__global__ __launch_bounds__(1024) void k_scanA(int* __restrict__ HM,
                                                int* __restrict__ bsum, int n) {
    __shared__ int s[1024];
    int t = threadIdx.x;
    int idx = blockIdx.x * 1024 + t;
    int v = (idx < n) ? HM[idx] : 0;
    s[t] = v;
    __syncthreads();
    for (int off = 1; off < 1024; off <<= 1) {
        int add = (t >= off) ? s[t - off] : 0;
        __syncthreads();
        s[t] += add;
        __syncthreads();
    }
    if (idx < n) HM[idx] = s[t] - v;            // exclusive within block
    if (t == 1023) bsum[blockIdx.x] = s[t];     // block total
}

// ---------------- scan pass 2: serial scan of block sums ----------------------
__global__ void k_scan2(const int* __restrict__ bsum, int* __restrict__ boff, int nb) {
    if (threadIdx.x == 0 && blockIdx.x == 0) {
        int acc = 0;
        for (int b = 0; b < nb; b++) { boff[b] = acc; acc += bsum[b]; }
        boff[nb] = acc;
    }
}

// ---------------- scan pass 3: add block offsets ------------------------------
__global__ void k_scanC(int* __restrict__ HM, const int* __restrict__ boff, int n) {
    int idx = blockIdx.x * blockDim.x + threadIdx.x;
    if (idx < n) HM[idx] += boff[idx >> 10];
}

// ---------------- pass C: place edges (LDS cursors, deterministic ranges) ----
// part[pos] = src | (dst&255)<<17
__global__ __launch_bounds__(256) void k_place(const int* __restrict__ src,
                                               const int* __restrict__ dst,
                                               const int* __restrict__ HM,
                                               int* __restrict__ part, int E) {
    __shared__ int cur[NBUCK];
    int blk = blockIdx.x, t = threadIdx.x;
    for (int i = t; i < NBUCK; i += 256) cur[i] = HM[i * NPB + blk];
    __syncthreads();
    int beg = blk * CHUNK, end = min(E, beg + CHUNK);
    for (int j = beg + t; j < end; j += 256) {
        int d = dst[j], s = src[j];
        int pos = atomicAdd(&cur[d >> 8], 1);   // LDS atomic — no global contention
        part[pos] = s | ((d & 255) << 17);
    }
}

// ---------------- phase B: per-bucket fine sort + degree + rowptr + dinv -----
__global__ __launch_bounds__(256) void k_phaseB(const int* __restrict__ part,
                                                const int* __restrict__ HM,
                                                int* __restrict__ rowptr,
                                                int* __restrict__ ssrc,
                                                float* __restrict__ dinv, int E) {
    __shared__ int cnt[256];
    __shared__ int sc[256];
    int b = blockIdx.x;
    int t = threadIdx.x;
    int beg = HM[b * NPB];
    int end = (b == NBUCK - 1) ? E : HM[(b + 1) * NPB];
    int node0 = b << 8;
    int nnode = NN - node0 < 256 ? NN - node0 : 256;
    cnt[t] = 0;
    __syncthreads();
    for (int j = beg + t; j < end; j += 256) atomicAdd(&cnt[part[j] >> 17], 1);
    __syncthreads();
    int v = cnt[t];
    sc[t] = v;
    __syncthreads();
    for (int off = 1; off < 256; off <<= 1) {
        int add = (t >= off) ? sc[t - off] : 0;
        __syncthreads();
        sc[t] += add;
        __syncthreads();
    }
    int excl = sc[t] - v;
    if (t < nnode) {
        rowptr[node0 + t] = beg + excl;
        dinv[node0 + t] = rsqrtf((float)v + 1.0f);
    }
    if (b == NBUCK - 1 && t == 0) rowptr[NN] = E;
    __syncthreads();
    cnt[t] = beg + excl;    // reuse as cursor
    __syncthreads();
    for (int j = beg + t; j < end; j += 256) {
        int e = part[j];
        int pos = atomicAdd(&cnt[e >> 17], 1);
        ssrc[pos] = e & 0x1FFFF;
    }
}

// ---------------- GEMM: U[n][64] = (X[n][K] @ W[K][64]) * dinv[row] ----------
template <int K>
__global__ void k_gemm(const float* __restrict__ X, const float* __restrict__ W,
                       const float* __restrict__ dinv, float* __restrict__ U, int n) {
    __shared__ __align__(16) float wl[K * 64];
    __shared__ __align__(16) float xs[16][K];
    int tid = threadIdx.x;
    for (int i = tid; i < K * 64; i += 256) wl[i] = W[i];
    int cg = tid & 15;
    int rs = tid >> 4;
    int ngrp = (n + 15) >> 4;
    for (int grp = blockIdx.x; grp < ngrp; grp += gridDim.x) {
        int row0 = grp * 16;
        __syncthreads();
        for (int i = tid; i < 16 * K; i += 256) {
            int r = i / K, c = i % K;
            int row = row0 + r;
            xs[r][c] = (row < n) ? X[(size_t)row * K + c] : 0.0f;
        }
        __syncthreads();
        float4 acc = {0.f, 0.f, 0.f, 0.f};
#pragma unroll 8
        for (int k = 0; k < K; k++) {
            float xv = xs[rs][k];
            float4 w4 = *reinterpret_cast<const float4*>(&wl[k * 64 + cg * 4]);
            acc.x += xv * w4.x;
            acc.y += xv * w4.y;
            acc.z += xv * w4.z;
            acc.w += xv * w4.w;
        }
        int row = row0 + rs;
        if (row < n) {
            float dv = dinv[row];
            acc.x *= dv; acc.y *= dv; acc.z *= dv; acc.w *= dv;
            *reinterpret_cast<float4*>(&U[(size_t)row * 64 + cg * 4]) = acc;
        }
    }
}

// ---------------- gather-reduce per dst node ----------------------------------
// h[d] = relu(dinv[d] * (sum_{s in N(d)} U[s] + U[d]) + b)
template <bool FUSE_POOL>
__global__ void k_gather(const int* __restrict__ rowptr, const int* __restrict__ ssrc,
                         const float* __restrict__ dinv, const float* __restrict__ U,
                         const float* __restrict__ bias, const int* __restrict__ batch,
                         float* __restrict__ outbuf, int n) {
    int gtid = blockIdx.x * blockDim.x + threadIdx.x;
    int lane = gtid & 63;
    int g = lane >> 4;       // edge sub-index within a 4-edge chunk
    int c = lane & 15;       // float4 chunk within the 64-ch row
    int w = gtid >> 6;
    int nw = (gridDim.x * blockDim.x) >> 6;
    float4 bv = *reinterpret_cast<const float4*>(&bias[c * 4]);
    for (int d = w; d < n; d += nw) {
        int beg = rowptr[d], end = rowptr[d + 1];
        float4 acc0 = {0.f, 0.f, 0.f, 0.f};
        float4 acc1 = {0.f, 0.f, 0.f, 0.f};
        int j = beg;
        for (; j + 8 <= end; j += 8) {
            int s0 = ssrc[j + g];
            int s1 = ssrc[j + 4 + g];
            float4 v0 = *reinterpret_cast<const float4*>(&U[(size_t)s0 * 64 + c * 4]);
            float4 v1 = *reinterpret_cast<const float4*>(&U[(size_t)s1 * 64 + c * 4]);
            acc0.x += v0.x; acc0.y += v0.y; acc0.z += v0.z; acc0.w += v0.w;
            acc1.x += v1.x; acc1.y += v1.y; acc1.z += v1.z; acc1.w += v1.w;
        }
        if (j + 4 <= end) {
            int s0 = ssrc[j + g];
            float4 v0 = *reinterpret_cast<const float4*>(&U[(size_t)s0 * 64 + c * 4]);
            acc0.x += v0.x; acc0.y += v0.y; acc0.z += v0.z; acc0.w += v0.w;
            j += 4;
        }
        if (j + g < end) {
            int s1 = ssrc[j + g];
            float4 v1 = *reinterpret_cast<const float4*>(&U[(size_t)s1 * 64 + c * 4]);
            acc1.x += v1.x; acc1.y += v1.y; acc1.z += v1.z; acc1.w += v1.w;
        }
        acc0.x += acc1.x; acc0.y += acc1.y; acc0.z += acc1.z; acc0.w += acc1.w;
        acc0.x += __shfl_xor(acc0.x, 16); acc0.y += __shfl_xor(acc0.y, 16);
        acc0.z += __shfl_xor(acc0.z, 16); acc0.w += __shfl_xor(acc0.w, 16);
        acc0.x += __shfl_xor(acc0.x, 32); acc0.y += __shfl_xor(acc0.y, 32);
        acc0.z += __shfl_xor(acc0.z, 32); acc0.w += __shfl_xor(acc0.w, 32);
        float4 ud = *reinterpret_cast<const float4*>(&U[(size_t)d * 64 + c * 4]);
        float dd = dinv[d];
        float4 h;
        h.x = (acc0.x + ud.x) * dd + bv.x;
        h.y = (acc0.y + ud.y) * dd + bv.y;
        h.z = (acc0.z + ud.z) * dd + bv.z;
        h.w = (acc0.w + ud.w) * dd + bv.w;
        h.x = h.x > 0.f ? h.x : 0.f;
        h.y = h.y > 0.f ? h.y : 0.f;
        h.z = h.z > 0.f ? h.z : 0.f;
        h.w = h.w > 0.f ? h.w : 0.f;
        if (FUSE_POOL) {
            if (g == 0) {
                float* sp = &outbuf[(size_t)batch[d] * 64 + c * 4];
                atomicAdd(sp + 0, h.x);
                atomicAdd(sp + 1, h.y);
                atomicAdd(sp + 2, h.z);
                atomicAdd(sp + 3, h.w);
            }
        } else {
            if (g == 0) {
                *reinterpret_cast<float4*>(&outbuf[(size_t)d * 64 + c * 4]) = h;
            }
        }
    }
}

// ---------------- per-graph node counts ---------------------------------------
__global__ void k_cnt(const int* __restrict__ batch, float* __restrict__ cnt, int n) {
    int i = blockIdx.x * blockDim.x + threadIdx.x;
    if (i < n) atomicAdd(&cnt[batch[i]], 1.0f);
}

// ---------------- head: out[g] = (sums[g]/cnt[g]) @ Wl + bl ------------------
__global__ void k_final(const float* __restrict__ sums, const float* __restrict__ cnt,
                        const float* __restrict__ Wl, const float* __restrict__ bl,
                        float* __restrict__ out) {
    __shared__ float pooled[64];
    int g = blockIdx.x;
    int t = threadIdx.x;
    float c = cnt[g];
    c = c < 1.0f ? 1.0f : c;
    pooled[t] = sums[g * 64 + t] / c;
    __syncthreads();
    if (t < 32) {
        float acc = bl[t];
#pragma unroll 8
        for (int k = 0; k < 64; k++) acc += pooled[k] * Wl[k * 32 + t];
        out[g * 32 + t] = acc;
    }
}

extern "C" void kernel_launch(void* const* d_in, const int* in_sizes, int n_in,
                              void* d_out, int out_size, void* d_ws, size_t ws_size,
                              hipStream_t stream) {
    const float* x = (const float*)d_in[0];
    const int* ei = (const int*)d_in[1];      // [2, E] int32
    const int* batch = (const int*)d_in[2];   // [N] int32
    const float* W1 = (const float*)d_in[4];
    const float* b1 = (const float*)d_in[5];
    const float* W2 = (const float*)d_in[6];
    const float* b2 = (const float*)d_in[7];
    const float* Wl = (const float*)d_in[8];
    const float* bl = (const float*)d_in[9];
    float* out = (float*)d_out;

    const int* esrc = ei;
    const int* edst = ei + NE;

    char* ws = (char*)d_ws;
    size_t off = 0;
    auto alloc = [&](size_t bytes) {
        void* p = ws + off;
        off += (bytes + 255) & ~size_t(255);
        return p;
    };
    float* dinv   = (float*)alloc((size_t)NN * 4);
    int*   rowptr = (int*)alloc((size_t)(NN + 1) * 4);
    int*   HM     = (int*)alloc((size_t)NM * 4);        // 0.8 MB scan matrix
    int*   bsum   = (int*)alloc((size_t)(NMB + 1) * 4);
    int*   boff   = (int*)alloc((size_t)(NMB + 1) * 4);
    int*   ssrc   = (int*)alloc((size_t)NE * 4);        // 12.8 MB
    float* tbuf   = (float*)alloc((size_t)NN * HD * 4); // 25.6 MB
    float* agg    = (float*)alloc((size_t)NN * HD * 4); // 25.6 MB
    float* sums   = (float*)alloc((size_t)NG * HD * 4);
    float* cnt    = (float*)alloc((size_t)NG * 4);
    // part overlays tbuf: dead before gemm1 writes tbuf
    int* part = (int*)tbuf;

    // 1. contention-free radix partition -> ssrc (+ rowptr, dinv)
    k_blkhist<<<NPB, 256, 0, stream>>>(edst, HM, NE);
    k_scanA<<<NMB, 1024, 0, stream>>>(HM, bsum, NM);
    k_scan2<<<1, 64, 0, stream>>>(bsum, boff, NMB);
    k_scanC<<<(NM + 255) / 256, 256, 0, stream>>>(HM, boff, NM);
    k_place<<<NPB, 256, 0, stream>>>(esrc, edst, HM, part, NE);
    k_phaseB<<<NBUCK, 256, 0, stream>>>(part, HM, rowptr, ssrc, dinv, NE);

    // 2. layer 1: U1 = (x@W1)*dinv ; h1 = relu(dinv*(gather+self) + b1) -> agg
    k_gemm<DIN><<<512, 256, 0, stream>>>(x, W1, dinv, tbuf, NN);
    k_gather<false><<<2048, 256, 0, stream>>>(rowptr, ssrc, dinv, tbuf, b1, batch, agg, NN);

    // 3. layer 2: U2 = (h1@W2)*dinv ; h2 rows scattered straight into pool sums
    k_gemm<HD><<<512, 256, 0, stream>>>(agg, W2, dinv, tbuf, NN);
    hipMemsetAsync(sums, 0, (size_t)(NG * HD + NG) * 4, stream);  // sums + cnt
    k_cnt<<<(NN + 255) / 256, 256, 0, stream>>>(batch, cnt, NN);
    k_gather<true><<<2048, 256, 0, stream>>>(rowptr, ssrc, dinv, tbuf, b2, batch, sums, NN);

    // 4. head
    k_final<<<NG, 64, 0, stream>>>(sums, cnt, Wl, bl, out);
}

// Round 7
// 666.332 us; speedup vs baseline: 2.8154x; 1.1931x over previous
//
#include <hip/hip_runtime.h>

#define NN 100000
#define NE 3200000
#define DIN 128
#define HD 64
#define DEMB 32
#define NG 256
#define NBUCK ((NN + 255) / 256)        // 391 coarse buckets of 256 dst-nodes
#define NPB 512                         // partition blocks
#define CHUNK ((NE + NPB - 1) / NPB)    // 6250 edges per partition block
#define NM (NBUCK * NPB)                // 200192 histogram-matrix entries
#define NMB ((NM + 1023) / 1024)        // 196 scan blocks

// ---------------- pass A: per-block coarse histogram (no global atomics) -----
__global__ __launch_bounds__(256) void k_blkhist(const int* __restrict__ dst,
                                                 int* __restrict__ HM, int E) {
    __shared__ int h[NBUCK];
    int blk = blockIdx.x, t = threadIdx.x;
    for (int i = t; i < NBUCK; i += 256) h[i] = 0;
    __syncthreads();
    int beg = blk * CHUNK, end = min(E, beg + CHUNK);
    for (int j = beg + t; j < end; j += 256) atomicAdd(&h[dst[j] >> 8], 1);
    __syncthreads();
    for (int i = t; i < NBUCK; i += 256) HM[i * NPB + blk] = h[i];  // bucket-major
}

// ---------------- scan pass 1: in-place per-1024-block exclusive scan --------
__global__ __launch_bounds__(1024) void k_scanA(int* __restrict__ HM,
                                                int* __restrict__ bsum, int n) {
    __shared__ int s[1024];
    int t = threadIdx.x;
    int idx = blockIdx.x * 1024 + t;
    int v = (idx < n) ? HM[idx] : 0;
    s[t] = v;
    __syncthreads();
    for (int off = 1; off < 1024; off <<= 1) {
        int add = (t >= off) ? s[t - off] : 0;
        __syncthreads();
        s[t] += add;
        __syncthreads();
    }
    if (idx < n) HM[idx] = s[t] - v;            // exclusive within block
    if (t == 1023) bsum[blockIdx.x] = s[t];     // block total
}

// ---------------- scan pass 2: serial scan of block sums ----------------------
__global__ void k_scan2(const int* __restrict__ bsum, int* __restrict__ boff, int nb) {
    if (threadIdx.x == 0 && blockIdx.x == 0) {
        int acc = 0;
        for (int b = 0; b < nb; b++) { boff[b] = acc; acc += bsum[b]; }
        boff[nb] = acc;
    }
}

// ---------------- scan pass 3: add block offsets ------------------------------
__global__ void k_scanC(int* __restrict__ HM, const int* __restrict__ boff, int n) {
    int idx = blockIdx.x * blockDim.x + threadIdx.x;
    if (idx < n) HM[idx] += boff[idx >> 10];
}

// ---------------- pass C: place edges (LDS cursors, deterministic ranges) ----
// part[pos] = src | (dst&255)<<17
__global__ __launch_bounds__(256) void k_place(const int* __restrict__ src,
                                               const int* __restrict__ dst,
                                               const int* __restrict__ HM,
                                               int* __restrict__ part, int E) {
    __shared__ int cur[NBUCK];
    int blk = blockIdx.x, t = threadIdx.x;
    for (int i = t; i < NBUCK; i += 256) cur[i] = HM[i * NPB + blk];
    __syncthreads();
    int beg = blk * CHUNK, end = min(E, beg + CHUNK);
    for (int j = beg + t; j < end; j += 256) {
        int d = dst[j], s = src[j];
        int pos = atomicAdd(&cur[d >> 8], 1);   // LDS atomic — no global contention
        part[pos] = s | ((d & 255) << 17);
    }
}

// ---------------- phase B: per-bucket fine sort + degree + rowptr + dinv -----
__global__ __launch_bounds__(256) void k_phaseB(const int* __restrict__ part,
                                                const int* __restrict__ HM,
                                                int* __restrict__ rowptr,
                                                int* __restrict__ ssrc,
                                                float* __restrict__ dinv, int E) {
    __shared__ int cnt[256];
    __shared__ int sc[256];
    int b = blockIdx.x;
    int t = threadIdx.x;
    int beg = HM[b * NPB];
    int end = (b == NBUCK - 1) ? E : HM[(b + 1) * NPB];
    int node0 = b << 8;
    int nnode = NN - node0 < 256 ? NN - node0 : 256;
    cnt[t] = 0;
    __syncthreads();
    for (int j = beg + t; j < end; j += 256) atomicAdd(&cnt[part[j] >> 17], 1);
    __syncthreads();
    int v = cnt[t];
    sc[t] = v;
    __syncthreads();
    for (int off = 1; off < 256; off <<= 1) {
        int add = (t >= off) ? sc[t - off] : 0;
        __syncthreads();
        sc[t] += add;
        __syncthreads();
    }
    int excl = sc[t] - v;
    if (t < nnode) {
        rowptr[node0 + t] = beg + excl;
        dinv[node0 + t] = rsqrtf((float)v + 1.0f);
    }
    if (b == NBUCK - 1 && t == 0) rowptr[NN] = E;
    __syncthreads();
    cnt[t] = beg + excl;    // reuse as cursor
    __syncthreads();
    for (int j = beg + t; j < end; j += 256) {
        int e = part[j];
        int pos = atomicAdd(&cnt[e >> 17], 1);
        ssrc[pos] = e & 0x1FFFF;
    }
}

// ---------------- GEMM: U[n][64] = (X[n][K] @ W[K][64]) * dinv[row] ----------
template <int K>
__global__ void k_gemm(const float* __restrict__ X, const float* __restrict__ W,
                       const float* __restrict__ dinv, float* __restrict__ U, int n) {
    __shared__ __align__(16) float wl[K * 64];
    __shared__ __align__(16) float xs[16][K];
    int tid = threadIdx.x;
    for (int i = tid; i < K * 64; i += 256) wl[i] = W[i];
    int cg = tid & 15;
    int rs = tid >> 4;
    int ngrp = (n + 15) >> 4;
    for (int grp = blockIdx.x; grp < ngrp; grp += gridDim.x) {
        int row0 = grp * 16;
        __syncthreads();
        for (int i = tid; i < 16 * K; i += 256) {
            int r = i / K, c = i % K;
            int row = row0 + r;
            xs[r][c] = (row < n) ? X[(size_t)row * K + c] : 0.0f;
        }
        __syncthreads();
        float4 acc = {0.f, 0.f, 0.f, 0.f};
#pragma unroll 8
        for (int k = 0; k < K; k++) {
            float xv = xs[rs][k];
            float4 w4 = *reinterpret_cast<const float4*>(&wl[k * 64 + cg * 4]);
            acc.x += xv * w4.x;
            acc.y += xv * w4.y;
            acc.z += xv * w4.z;
            acc.w += xv * w4.w;
        }
        int row = row0 + rs;
        if (row < n) {
            float dv = dinv[row];
            acc.x *= dv; acc.y *= dv; acc.z *= dv; acc.w *= dv;
            *reinterpret_cast<float4*>(&U[(size_t)row * 64 + cg * 4]) = acc;
        }
    }
}

// ---------------- gather-reduce per dst node ----------------------------------
// h[d] = relu(dinv[d] * (sum_{s in N(d)} U[s] + U[d]) + b)
// lane mapping: g = lane&3 (edge slot), c = lane>>2 (float4 chunk).
// After shfl_xor(1),(2) reduce, channel == lane -> fully coalesced 4B/lane store.
// 4 independent dwordx4 loads per iter = 16 edges / 4KB in flight per wave.
template <bool FUSE_POOL>
__global__ void k_gather(const int* __restrict__ rowptr, const int* __restrict__ ssrc,
                         const float* __restrict__ dinv, const float* __restrict__ U,
                         const float* __restrict__ bias, const int* __restrict__ batch,
                         float* __restrict__ outbuf, int n) {
    int gtid = blockIdx.x * blockDim.x + threadIdx.x;
    int lane = gtid & 63;
    int g = lane & 3;        // edge slot within 4-edge chunk
    int c = lane >> 2;       // float4 chunk within the 64-ch row (0..15)
    int w = gtid >> 6;
    int nw = (gridDim.x * blockDim.x) >> 6;
    float bv = bias[lane];
    for (int d = w; d < n; d += nw) {
        int beg = rowptr[d], end = rowptr[d + 1];
        float4 a0 = {0.f, 0.f, 0.f, 0.f};
        float4 a1 = {0.f, 0.f, 0.f, 0.f};
        float4 a2 = {0.f, 0.f, 0.f, 0.f};
        float4 a3 = {0.f, 0.f, 0.f, 0.f};
        int j = beg;
        for (; j + 16 <= end; j += 16) {
            int s0 = ssrc[j + g];
            int s1 = ssrc[j + 4 + g];
            int s2 = ssrc[j + 8 + g];
            int s3 = ssrc[j + 12 + g];
            float4 v0 = *reinterpret_cast<const float4*>(&U[(size_t)s0 * 64 + c * 4]);
            float4 v1 = *reinterpret_cast<const float4*>(&U[(size_t)s1 * 64 + c * 4]);
            float4 v2 = *reinterpret_cast<const float4*>(&U[(size_t)s2 * 64 + c * 4]);
            float4 v3 = *reinterpret_cast<const float4*>(&U[(size_t)s3 * 64 + c * 4]);
            a0.x += v0.x; a0.y += v0.y; a0.z += v0.z; a0.w += v0.w;
            a1.x += v1.x; a1.y += v1.y; a1.z += v1.z; a1.w += v1.w;
            a2.x += v2.x; a2.y += v2.y; a2.z += v2.z; a2.w += v2.w;
            a3.x += v3.x; a3.y += v3.y; a3.z += v3.z; a3.w += v3.w;
        }
        for (; j + 4 <= end; j += 4) {
            int s0 = ssrc[j + g];
            float4 v0 = *reinterpret_cast<const float4*>(&U[(size_t)s0 * 64 + c * 4]);
            a0.x += v0.x; a0.y += v0.y; a0.z += v0.z; a0.w += v0.w;
        }
        if (j + g < end) {
            int s1 = ssrc[j + g];
            float4 v1 = *reinterpret_cast<const float4*>(&U[(size_t)s1 * 64 + c * 4]);
            a1.x += v1.x; a1.y += v1.y; a1.z += v1.z; a1.w += v1.w;
        }
        a0.x += a1.x + a2.x + a3.x;
        a0.y += a1.y + a2.y + a3.y;
        a0.z += a1.z + a2.z + a3.z;
        a0.w += a1.w + a2.w + a3.w;
        // reduce over g: lanes xor 1 and 2 (within each 4-lane chunk group)
        a0.x += __shfl_xor(a0.x, 1); a0.y += __shfl_xor(a0.y, 1);
        a0.z += __shfl_xor(a0.z, 1); a0.w += __shfl_xor(a0.w, 1);
        a0.x += __shfl_xor(a0.x, 2); a0.y += __shfl_xor(a0.y, 2);
        a0.z += __shfl_xor(a0.z, 2); a0.w += __shfl_xor(a0.w, 2);
        // channel = c*4 + g = lane; pick this lane's component
        float hv = (g == 0) ? a0.x : (g == 1) ? a0.y : (g == 2) ? a0.z : a0.w;
        float ud = U[(size_t)d * 64 + lane];   // coalesced 256B wave read
        float dd = dinv[d];
        float h = (hv + ud) * dd + bv;
        h = h > 0.f ? h : 0.f;
        if (FUSE_POOL) {
            atomicAdd(&outbuf[(size_t)batch[d] * 64 + lane], h);
        } else {
            outbuf[(size_t)d * 64 + lane] = h;  // coalesced 256B wave store
        }
    }
}

// ---------------- per-graph node counts ---------------------------------------
__global__ void k_cnt(const int* __restrict__ batch, float* __restrict__ cnt, int n) {
    int i = blockIdx.x * blockDim.x + threadIdx.x;
    if (i < n) atomicAdd(&cnt[batch[i]], 1.0f);
}

// ---------------- head: out[g] = (sums[g]/cnt[g]) @ Wl + bl ------------------
__global__ void k_final(const float* __restrict__ sums, const float* __restrict__ cnt,
                        const float* __restrict__ Wl, const float* __restrict__ bl,
                        float* __restrict__ out) {
    __shared__ float pooled[64];
    int g = blockIdx.x;
    int t = threadIdx.x;
    float c = cnt[g];
    c = c < 1.0f ? 1.0f : c;
    pooled[t] = sums[g * 64 + t] / c;
    __syncthreads();
    if (t < 32) {
        float acc = bl[t];
#pragma unroll 8
        for (int k = 0; k < 64; k++) acc += pooled[k] * Wl[k * 32 + t];
        out[g * 32 + t] = acc;
    }
}

extern "C" void kernel_launch(void* const* d_in, const int* in_sizes, int n_in,
                              void* d_out, int out_size, void* d_ws, size_t ws_size,
                              hipStream_t stream) {
    const float* x = (const float*)d_in[0];
    const int* ei = (const int*)d_in[1];      // [2, E] int32
    const int* batch = (const int*)d_in[2];   // [N] int32
    const float* W1 = (const float*)d_in[4];
    const float* b1 = (const float*)d_in[5];
    const float* W2 = (const float*)d_in[6];
    const float* b2 = (const float*)d_in[7];
    const float* Wl = (const float*)d_in[8];
    const float* bl = (const float*)d_in[9];
    float* out = (float*)d_out;

    const int* esrc = ei;
    const int* edst = ei + NE;

    char* ws = (char*)d_ws;
    size_t off = 0;
    auto alloc = [&](size_t bytes) {
        void* p = ws + off;
        off += (bytes + 255) & ~size_t(255);
        return p;
    };
    float* dinv   = (float*)alloc((size_t)NN * 4);
    int*   rowptr = (int*)alloc((size_t)(NN + 1) * 4);
    int*   HM     = (int*)alloc((size_t)NM * 4);        // 0.8 MB scan matrix
    int*   bsum   = (int*)alloc((size_t)(NMB + 1) * 4);
    int*   boff   = (int*)alloc((size_t)(NMB + 1) * 4);
    int*   ssrc   = (int*)alloc((size_t)NE * 4);        // 12.8 MB
    float* tbuf   = (float*)alloc((size_t)NN * HD * 4); // 25.6 MB
    float* agg    = (float*)alloc((size_t)NN * HD * 4); // 25.6 MB
    float* sums   = (float*)alloc((size_t)NG * HD * 4);
    float* cnt    = (float*)alloc((size_t)NG * 4);
    // part overlays tbuf: dead before gemm1 writes tbuf
    int* part = (int*)tbuf;

    // 1. contention-free radix partition -> ssrc (+ rowptr, dinv)
    k_blkhist<<<NPB, 256, 0, stream>>>(edst, HM, NE);
    k_scanA<<<NMB, 1024, 0, stream>>>(HM, bsum, NM);
    k_scan2<<<1, 64, 0, stream>>>(bsum, boff, NMB);
    k_scanC<<<(NM + 255) / 256, 256, 0, stream>>>(HM, boff, NM);
    k_place<<<NPB, 256, 0, stream>>>(esrc, edst, HM, part, NE);
    k_phaseB<<<NBUCK, 256, 0, stream>>>(part, HM, rowptr, ssrc, dinv, NE);

    // 2. layer 1: U1 = (x@W1)*dinv ; h1 = relu(dinv*(gather+self) + b1) -> agg
    k_gemm<DIN><<<512, 256, 0, stream>>>(x, W1, dinv, tbuf, NN);
    k_gather<false><<<2048, 256, 0, stream>>>(rowptr, ssrc, dinv, tbuf, b1, batch, agg, NN);

    // 3. layer 2: U2 = (h1@W2)*dinv ; h2 rows scattered straight into pool sums
    k_gemm<HD><<<512, 256, 0, stream>>>(agg, W2, dinv, tbuf, NN);
    hipMemsetAsync(sums, 0, (size_t)(NG * HD + NG) * 4, stream);  // sums + cnt
    k_cnt<<<(NN + 255) / 256, 256, 0, stream>>>(batch, cnt, NN);
    k_gather<true><<<2048, 256, 0, stream>>>(rowptr, ssrc, dinv, tbuf, b2, batch, sums, NN);

    // 4. head
    k_final<<<NG, 64, 0, stream>>>(sums, cnt, Wl, bl, out);
}

// Round 8
// 477.014 us; speedup vs baseline: 3.9328x; 1.3969x over previous
//
#include <hip/hip_runtime.h>

#define NN 100000
#define NE 3200000
#define DIN 128
#define HD 64
#define DEMB 32
#define NG 256
#define NBUCK ((NN + 255) / 256)        // 391 coarse buckets of 256 dst-nodes
#define NPB 512                         // partition blocks
#define CHUNK ((NE + NPB - 1) / NPB)    // 6250 edges per partition block
#define NM (NBUCK * NPB)                // 200192 histogram-matrix entries
#define NMB ((NM + 1023) / 1024)        // 196 scan blocks

// ---------------- pass A: per-block coarse histogram (no global atomics) -----
__global__ __launch_bounds__(256) void k_blkhist(const int* __restrict__ dst,
                                                 int* __restrict__ HM, int E) {
    __shared__ int h[NBUCK];
    int blk = blockIdx.x, t = threadIdx.x;
    for (int i = t; i < NBUCK; i += 256) h[i] = 0;
    __syncthreads();
    int beg = blk * CHUNK, end = min(E, beg + CHUNK);
    for (int j = beg + t; j < end; j += 256) atomicAdd(&h[dst[j] >> 8], 1);
    __syncthreads();
    for (int i = t; i < NBUCK; i += 256) HM[i * NPB + blk] = h[i];  // bucket-major
}

// ---------------- scan pass 1: in-place per-1024-block exclusive scan --------
__global__ __launch_bounds__(1024) void k_scanA(int* __restrict__ HM,
                                                int* __restrict__ bsum, int n) {
    __shared__ int s[1024];
    int t = threadIdx.x;
    int idx = blockIdx.x * 1024 + t;
    int v = (idx < n) ? HM[idx] : 0;
    s[t] = v;
    __syncthreads();
    for (int off = 1; off < 1024; off <<= 1) {
        int add = (t >= off) ? s[t - off] : 0;
        __syncthreads();
        s[t] += add;
        __syncthreads();
    }
    if (idx < n) HM[idx] = s[t] - v;            // exclusive within block
    if (t == 1023) bsum[blockIdx.x] = s[t];     // block total
}

// ---------------- scan pass 2: serial scan of block sums ----------------------
__global__ void k_scan2(const int* __restrict__ bsum, int* __restrict__ boff, int nb) {
    if (threadIdx.x == 0 && blockIdx.x == 0) {
        int acc = 0;
        for (int b = 0; b < nb; b++) { boff[b] = acc; acc += bsum[b]; }
        boff[nb] = acc;
    }
}

// ---------------- scan pass 3: add block offsets ------------------------------
__global__ void k_scanC(int* __restrict__ HM, const int* __restrict__ boff, int n) {
    int idx = blockIdx.x * blockDim.x + threadIdx.x;
    if (idx < n) HM[idx] += boff[idx >> 10];
}

// ---------------- pass C: place edges (LDS cursors, deterministic ranges) ----
// part[pos] = src | (dst&255)<<17
__global__ __launch_bounds__(256) void k_place(const int* __restrict__ src,
                                               const int* __restrict__ dst,
                                               const int* __restrict__ HM,
                                               int* __restrict__ part, int E) {
    __shared__ int cur[NBUCK];
    int blk = blockIdx.x, t = threadIdx.x;
    for (int i = t; i < NBUCK; i += 256) cur[i] = HM[i * NPB + blk];
    __syncthreads();
    int beg = blk * CHUNK, end = min(E, beg + CHUNK);
    for (int j = beg + t; j < end; j += 256) {
        int d = dst[j], s = src[j];
        int pos = atomicAdd(&cur[d >> 8], 1);   // LDS atomic — no global contention
        part[pos] = s | ((d & 255) << 17);
    }
}

// ---------------- phase B: per-bucket fine sort + degree + rowptr + dinv -----
__global__ __launch_bounds__(256) void k_phaseB(const int* __restrict__ part,
                                                const int* __restrict__ HM,
                                                int* __restrict__ rowptr,
                                                int* __restrict__ ssrc,
                                                float* __restrict__ dinv, int E) {
    __shared__ int cnt[256];
    __shared__ int sc[256];
    int b = blockIdx.x;
    int t = threadIdx.x;
    int beg = HM[b * NPB];
    int end = (b == NBUCK - 1) ? E : HM[(b + 1) * NPB];
    int node0 = b << 8;
    int nnode = NN - node0 < 256 ? NN - node0 : 256;
    cnt[t] = 0;
    __syncthreads();
    for (int j = beg + t; j < end; j += 256) atomicAdd(&cnt[part[j] >> 17], 1);
    __syncthreads();
    int v = cnt[t];
    sc[t] = v;
    __syncthreads();
    for (int off = 1; off < 256; off <<= 1) {
        int add = (t >= off) ? sc[t - off] : 0;
        __syncthreads();
        sc[t] += add;
        __syncthreads();
    }
    int excl = sc[t] - v;
    if (t < nnode) {
        rowptr[node0 + t] = beg + excl;
        dinv[node0 + t] = rsqrtf((float)v + 1.0f);
    }
    if (b == NBUCK - 1 && t == 0) rowptr[NN] = E;
    __syncthreads();
    cnt[t] = beg + excl;    // reuse as cursor
    __syncthreads();
    for (int j = beg + t; j < end; j += 256) {
        int e = part[j];
        int pos = atomicAdd(&cnt[e >> 17], 1);
        ssrc[pos] = e & 0x1FFFF;
    }
}

// ---------------- GEMM: U[n][64] = (X[n][K] @ W[K][64]) * dinv[row] ----------
template <int K>
__global__ void k_gemm(const float* __restrict__ X, const float* __restrict__ W,
                       const float* __restrict__ dinv, float* __restrict__ U, int n) {
    __shared__ __align__(16) float wl[K * 64];
    __shared__ __align__(16) float xs[16][K];
    int tid = threadIdx.x;
    for (int i = tid; i < K * 64; i += 256) wl[i] = W[i];
    int cg = tid & 15;
    int rs = tid >> 4;
    int ngrp = (n + 15) >> 4;
    for (int grp = blockIdx.x; grp < ngrp; grp += gridDim.x) {
        int row0 = grp * 16;
        __syncthreads();
        for (int i = tid; i < 16 * K; i += 256) {
            int r = i / K, c = i % K;
            int row = row0 + r;
            xs[r][c] = (row < n) ? X[(size_t)row * K + c] : 0.0f;
        }
        __syncthreads();
        float4 acc = {0.f, 0.f, 0.f, 0.f};
#pragma unroll 8
        for (int k = 0; k < K; k++) {
            float xv = xs[rs][k];
            float4 w4 = *reinterpret_cast<const float4*>(&wl[k * 64 + cg * 4]);
            acc.x += xv * w4.x;
            acc.y += xv * w4.y;
            acc.z += xv * w4.z;
            acc.w += xv * w4.w;
        }
        int row = row0 + rs;
        if (row < n) {
            float dv = dinv[row];
            acc.x *= dv; acc.y *= dv; acc.z *= dv; acc.w *= dv;
            *reinterpret_cast<float4*>(&U[(size_t)row * 64 + cg * 4]) = acc;
        }
    }
}

// ---------------- gather-reduce per dst node ----------------------------------
// h[d] = relu(dinv[d] * (sum_{s in N(d)} U[s] + U[d]) + b)
// lane mapping: g = lane&3 (edge slot), c = lane>>2 (float4 chunk).
// After shfl_xor(1),(2) reduce, channel == lane -> fully coalesced 4B/lane store.
__global__ void k_gather(const int* __restrict__ rowptr, const int* __restrict__ ssrc,
                         const float* __restrict__ dinv, const float* __restrict__ U,
                         const float* __restrict__ bias,
                         float* __restrict__ outbuf, int n) {
    int gtid = blockIdx.x * blockDim.x + threadIdx.x;
    int lane = gtid & 63;
    int g = lane & 3;        // edge slot within 4-edge chunk
    int c = lane >> 2;       // float4 chunk within the 64-ch row (0..15)
    int w = gtid >> 6;
    int nw = (gridDim.x * blockDim.x) >> 6;
    float bv = bias[lane];
    for (int d = w; d < n; d += nw) {
        int beg = rowptr[d], end = rowptr[d + 1];
        float4 a0 = {0.f, 0.f, 0.f, 0.f};
        float4 a1 = {0.f, 0.f, 0.f, 0.f};
        float4 a2 = {0.f, 0.f, 0.f, 0.f};
        float4 a3 = {0.f, 0.f, 0.f, 0.f};
        int j = beg;
        for (; j + 16 <= end; j += 16) {
            int s0 = ssrc[j + g];
            int s1 = ssrc[j + 4 + g];
            int s2 = ssrc[j + 8 + g];
            int s3 = ssrc[j + 12 + g];
            float4 v0 = *reinterpret_cast<const float4*>(&U[(size_t)s0 * 64 + c * 4]);
            float4 v1 = *reinterpret_cast<const float4*>(&U[(size_t)s1 * 64 + c * 4]);
            float4 v2 = *reinterpret_cast<const float4*>(&U[(size_t)s2 * 64 + c * 4]);
            float4 v3 = *reinterpret_cast<const float4*>(&U[(size_t)s3 * 64 + c * 4]);
            a0.x += v0.x; a0.y += v0.y; a0.z += v0.z; a0.w += v0.w;
            a1.x += v1.x; a1.y += v1.y; a1.z += v1.z; a1.w += v1.w;
            a2.x += v2.x; a2.y += v2.y; a2.z += v2.z; a2.w += v2.w;
            a3.x += v3.x; a3.y += v3.y; a3.z += v3.z; a3.w += v3.w;
        }
        for (; j + 4 <= end; j += 4) {
            int s0 = ssrc[j + g];
            float4 v0 = *reinterpret_cast<const float4*>(&U[(size_t)s0 * 64 + c * 4]);
            a0.x += v0.x; a0.y += v0.y; a0.z += v0.z; a0.w += v0.w;
        }
        if (j + g < end) {
            int s1 = ssrc[j + g];
            float4 v1 = *reinterpret_cast<const float4*>(&U[(size_t)s1 * 64 + c * 4]);
            a1.x += v1.x; a1.y += v1.y; a1.z += v1.z; a1.w += v1.w;
        }
        a0.x += a1.x + a2.x + a3.x;
        a0.y += a1.y + a2.y + a3.y;
        a0.z += a1.z + a2.z + a3.z;
        a0.w += a1.w + a2.w + a3.w;
        // reduce over g: lanes xor 1 and 2 (within each 4-lane chunk group)
        a0.x += __shfl_xor(a0.x, 1); a0.y += __shfl_xor(a0.y, 1);
        a0.z += __shfl_xor(a0.z, 1); a0.w += __shfl_xor(a0.w, 1);
        a0.x += __shfl_xor(a0.x, 2); a0.y += __shfl_xor(a0.y, 2);
        a0.z += __shfl_xor(a0.z, 2); a0.w += __shfl_xor(a0.w, 2);
        // channel = c*4 + g = lane; pick this lane's component
        float hv = (g == 0) ? a0.x : (g == 1) ? a0.y : (g == 2) ? a0.z : a0.w;
        float ud = U[(size_t)d * 64 + lane];   // coalesced 256B wave read
        float dd = dinv[d];
        float h = (hv + ud) * dd + bv;
        h = h > 0.f ? h : 0.f;
        outbuf[(size_t)d * 64 + lane] = h;     // coalesced 256B wave store
    }
}

// ---------------- pool: segmented sum over sorted batch ----------------------
// one wave per 64 contiguous nodes; lane = channel; register-accumulate while
// graph id (wave-uniform, sorted) is constant; flush = 64 distinct-address atomics.
__global__ __launch_bounds__(256) void k_pool(const float* __restrict__ h,
                                              const int* __restrict__ batch,
                                              float* __restrict__ sums, int n) {
    int tid = blockIdx.x * blockDim.x + threadIdx.x;
    int wave = tid >> 6;
    int lane = tid & 63;
    int node0 = wave * 64;
    if (node0 >= n) return;
    int nodeEnd = min(n, node0 + 64);
    float acc = 0.f;
    int curg = batch[node0];
    for (int nd = node0; nd < nodeEnd; ++nd) {
        int g = batch[nd];
        if (g != curg) {
            atomicAdd(&sums[(size_t)curg * 64 + lane], acc);
            acc = 0.f;
            curg = g;
        }
        acc += h[(size_t)nd * 64 + lane];
    }
    atomicAdd(&sums[(size_t)curg * 64 + lane], acc);
}

// ---------------- head: out[g] = (sums[g]/cnt[g]) @ Wl + bl ------------------
// cnt[g] from binary search over sorted batch (no atomics anywhere).
__global__ void k_final(const float* __restrict__ sums, const int* __restrict__ batch,
                        const float* __restrict__ Wl, const float* __restrict__ bl,
                        float* __restrict__ out, int n) {
    __shared__ float pooled[64];
    int g = blockIdx.x;
    int t = threadIdx.x;
    // lower_bound(g)
    int lo = 0, hi = n;
    while (lo < hi) { int m = (lo + hi) >> 1; if (batch[m] < g) lo = m + 1; else hi = m; }
    // lower_bound(g+1)
    int lo2 = lo, hi2 = n;
    while (lo2 < hi2) { int m = (lo2 + hi2) >> 1; if (batch[m] < g + 1) lo2 = m + 1; else hi2 = m; }
    float c = (float)(lo2 - lo);
    c = c < 1.0f ? 1.0f : c;
    pooled[t] = sums[g * 64 + t] / c;
    __syncthreads();
    if (t < 32) {
        float acc = bl[t];
#pragma unroll 8
        for (int k = 0; k < 64; k++) acc += pooled[k] * Wl[k * 32 + t];
        out[g * 32 + t] = acc;
    }
}

extern "C" void kernel_launch(void* const* d_in, const int* in_sizes, int n_in,
                              void* d_out, int out_size, void* d_ws, size_t ws_size,
                              hipStream_t stream) {
    const float* x = (const float*)d_in[0];
    const int* ei = (const int*)d_in[1];      // [2, E] int32
    const int* batch = (const int*)d_in[2];   // [N] int32
    const float* W1 = (const float*)d_in[4];
    const float* b1 = (const float*)d_in[5];
    const float* W2 = (const float*)d_in[6];
    const float* b2 = (const float*)d_in[7];
    const float* Wl = (const float*)d_in[8];
    const float* bl = (const float*)d_in[9];
    float* out = (float*)d_out;

    const int* esrc = ei;
    const int* edst = ei + NE;

    char* ws = (char*)d_ws;
    size_t off = 0;
    auto alloc = [&](size_t bytes) {
        void* p = ws + off;
        off += (bytes + 255) & ~size_t(255);
        return p;
    };
    float* dinv   = (float*)alloc((size_t)NN * 4);
    int*   rowptr = (int*)alloc((size_t)(NN + 1) * 4);
    int*   HM     = (int*)alloc((size_t)NM * 4);        // 0.8 MB scan matrix
    int*   bsum   = (int*)alloc((size_t)(NMB + 1) * 4);
    int*   boff   = (int*)alloc((size_t)(NMB + 1) * 4);
    int*   ssrc   = (int*)alloc((size_t)NE * 4);        // 12.8 MB
    float* tbuf   = (float*)alloc((size_t)NN * HD * 4); // 25.6 MB
    float* agg    = (float*)alloc((size_t)NN * HD * 4); // 25.6 MB
    float* sums   = (float*)alloc((size_t)NG * HD * 4);
    // part overlays tbuf: dead before gemm1 writes tbuf
    int* part = (int*)tbuf;

    // 1. contention-free radix partition -> ssrc (+ rowptr, dinv)
    k_blkhist<<<NPB, 256, 0, stream>>>(edst, HM, NE);
    k_scanA<<<NMB, 1024, 0, stream>>>(HM, bsum, NM);
    k_scan2<<<1, 64, 0, stream>>>(bsum, boff, NMB);
    k_scanC<<<(NM + 255) / 256, 256, 0, stream>>>(HM, boff, NM);
    k_place<<<NPB, 256, 0, stream>>>(esrc, edst, HM, part, NE);
    k_phaseB<<<NBUCK, 256, 0, stream>>>(part, HM, rowptr, ssrc, dinv, NE);

    // 2. layer 1: U1 = (x@W1)*dinv ; h1 = relu(dinv*(gather+self) + b1) -> agg
    k_gemm<DIN><<<512, 256, 0, stream>>>(x, W1, dinv, tbuf, NN);
    k_gather<<<2048, 256, 0, stream>>>(rowptr, ssrc, dinv, tbuf, b1, agg, NN);

    // 3. layer 2: U2 = (h1@W2)*dinv ; h2 -> agg (h1 dead after gemm2)
    k_gemm<HD><<<512, 256, 0, stream>>>(agg, W2, dinv, tbuf, NN);
    k_gather<<<2048, 256, 0, stream>>>(rowptr, ssrc, dinv, tbuf, b2, agg, NN);

    // 4. pool (segmented, conflict-free flushes) + head (binary-search counts)
    hipMemsetAsync(sums, 0, (size_t)NG * HD * 4, stream);
    k_pool<<<(NN + 255) / 256, 256, 0, stream>>>(agg, batch, sums, NN);
    k_final<<<NG, 64, 0, stream>>>(sums, batch, Wl, bl, out, NN);
}